// Round 13
// baseline (109.570 us; speedup 1.0000x reference)
//
#include <hip/hip_runtime.h>
#include <hip/hip_bf16.h>

namespace {
constexpr int B   = 16;
constexpr int NS  = 1000;
constexpr int IN  = 128;
constexpr int OUT = 128;
constexpr int K   = 256;   // IN + OUT

typedef __attribute__((ext_vector_type(8))) short short8;
typedef __attribute__((ext_vector_type(4))) float f32x4;

__device__ __forceinline__ float fsigmoid(float x) {
  return 1.0f / (1.0f + __expf(-x));
}
__device__ __forceinline__ float ftanh(float x) {
  return 2.0f / (1.0f + __expf(-2.0f * x)) - 1.0f;
}
__device__ __forceinline__ unsigned int f2bf(float f) {
  unsigned int u = __builtin_bit_cast(unsigned int, f);
  u += 0x7fffu + ((u >> 16) & 1u);
  return u >> 16;
}
__device__ __forceinline__ unsigned int pack2(float lo, float hi) {
  return f2bf(lo) | (f2bf(hi) << 16);
}

// Block = (stock n, col-half). 4 waves = 4 gates. Grid 2000.
// Each wave: TWO private 8KB LDS buffers (double-buffer), filled by
// global_load_lds (zero VGPR cost). Counted vmcnt(10) keeps the next
// chunk's 10 loads in flight across every wait — the pipe never drains
// until the final chunk (T3/T4: never vmcnt(0) in the main loop).
// LDS: 4 waves x 16KB = 64KB; epilogue overlays gbuf f32 (g*1040+b*65+c).
__global__ __launch_bounds__(256, 2) void lstm_kernel(
    const float* __restrict__ xt, const float* __restrict__ hidden,
    const float* __restrict__ ct_1,
    const float* __restrict__ Wi, const float* __restrict__ bi,
    const float* __restrict__ Wo, const float* __restrict__ bo,
    const float* __restrict__ Wf, const float* __restrict__ bfp,
    const float* __restrict__ Wc, const float* __restrict__ bc,
    float* __restrict__ out) {
  __shared__ __align__(16) unsigned char smem[65536];

  const int bid  = blockIdx.x;
  const int n    = bid >> 1;
  const int half = bid & 1;    // cols half*64 .. +63
  const int tid  = threadIdx.x;
  const int g    = tid >> 6;   // gate 0..3 (one wave per gate)
  const int l    = tid & 63;
  const int g2   = l >> 4;     // k-octet in frags / row-sub in staging
  const int c16  = l & 15;     // frag column / colquad in staging

  const float* Wg = (g == 0) ? Wi : (g == 1) ? Wo : (g == 2) ? Wf : Wc;
  const float* bg = (g == 0) ? bi : (g == 1) ? bo : (g == 2) ? bfp : bc;

  unsigned char* buf0 = smem + (g << 14);         // wave's buffer A (8KB)
  unsigned char* buf1 = buf0 + 8192;              // wave's buffer B (8KB)
  const float* wcb = Wg + (size_t)n * (K * OUT) + half * 64;

  // stage chunk r (rows r*32..+31, this half's 64 cols, fp32): 8 x 1KB
  auto stage_chunk = [&](int r, unsigned char* buf) {
    #pragma unroll
    for (int i = 0; i < 8; ++i) {
      const int cq = (c16 + ((i >> 1) << 2)) & 15;   // source col rotation
      const float* src =
          wcb + (size_t)((r << 5) + (i << 2) + g2) * OUT + (cq << 2);
      __builtin_amdgcn_global_load_lds(
          (const __attribute__((address_space(1))) void*)src,
          (__attribute__((address_space(3))) void*)(buf + (i << 10)),
          16, 0, 0);
    }
  };
  // A-frag for chunk r: xh[row=c16][k=r*32+g2*8 .. +7] direct from global
  auto load_a = [&](int r, float4& x0, float4& x1) {
    const int k = (r << 5) + (g2 << 3);
    const float* s = (k < IN) ? (xt + ((size_t)c16 * NS + n) * IN + k)
                              : (hidden + (size_t)n * OUT + (k - IN));
    x0 = *reinterpret_cast<const float4*>(s);
    x1 = *reinterpret_cast<const float4*>(s + 4);
  };

  f32x4 acc[4] = {f32x4{0,0,0,0}, f32x4{0,0,0,0}, f32x4{0,0,0,0}, f32x4{0,0,0,0}};

  // one K-step; issues chunk r+2 into the same buffer after its reads drain
  auto kstep = [&](int r, float4& cA0, float4& cA1, unsigned char* buf) {
    // chunk r resident; chunk r+1 (8 stage + 2 A loads) stays in flight
    if (r >= 7) asm volatile("s_waitcnt vmcnt(0)" ::: "memory");
    else        asm volatile("s_waitcnt vmcnt(10)" ::: "memory");

    float wv[4][8];
    #pragma unroll
    for (int t = 0; t < 4; ++t) {
      const int pb = (((((t << 2) + (c16 >> 2)) - (g2 << 2)) & 15) << 4) +
                     ((c16 & 3) << 2);
      #pragma unroll
      for (int j = 0; j < 8; ++j)
        wv[t][j] = *reinterpret_cast<const float*>(
            buf + (g2 << 11) + (j << 8) + pb);
    }
    asm volatile("s_waitcnt lgkmcnt(0)" ::: "memory");  // buf reads drained

    uint4 au;
    au.x = pack2(cA0.x, cA0.y); au.y = pack2(cA0.z, cA0.w);
    au.z = pack2(cA1.x, cA1.y); au.w = pack2(cA1.z, cA1.w);
    const short8 af = __builtin_bit_cast(short8, au);

    if (r < 6) {                 // issue A first, then stage: keeps counts exact
      load_a(r + 2, cA0, cA1);
      stage_chunk(r + 2, buf);   // overwrite safe: lgkmcnt(0) above
    }

    #pragma unroll
    for (int t = 0; t < 4; ++t) {
      uint4 bu;
      bu.x = pack2(wv[t][0], wv[t][1]);
      bu.y = pack2(wv[t][2], wv[t][3]);
      bu.z = pack2(wv[t][4], wv[t][5]);
      bu.w = pack2(wv[t][6], wv[t][7]);
      acc[t] = __builtin_amdgcn_mfma_f32_16x16x32_bf16(
          af, __builtin_bit_cast(short8, bu), acc[t], 0, 0, 0);
    }
  };

  // prologue: A(0), S(0), A(1), S(1)  — newest-10 = A(1)+S(1) for iter 0
  float4 aA0, aA1, aB0, aB1;
  load_a(0, aA0, aA1);
  stage_chunk(0, buf0);
  load_a(1, aB0, aB1);
  stage_chunk(1, buf1);

  #pragma unroll 1
  for (int rr = 0; rr < 8; rr += 2) {
    kstep(rr,     aA0, aA1, buf0);
    kstep(rr + 1, aB0, aB1, buf1);
  }

  // ---- epilogue: overlay gbuf (idx = g*1040 + b*65 + coll) ----
  __syncthreads();   // all waves' staging landed (vmcnt(0)) and reads done
  float* gb = reinterpret_cast<float*>(smem);
  #pragma unroll
  for (int t = 0; t < 4; ++t) {
    const int coll = (t << 4) + c16;                    // local col 0..63
    const float bias = bg[(size_t)n * OUT + half * 64 + coll];
    #pragma unroll
    for (int r2 = 0; r2 < 4; ++r2) {
      const int b = (g2 << 2) + r2;                     // C/D: row=(lane>>4)*4+reg
      gb[g * 1040 + b * 65 + coll] = acc[t][r2] + bias;
    }
  }
  __syncthreads();

  // ---- combine gates, write ht and ct (fp32 outputs) ----
  const size_t nbase = (size_t)n * OUT;
  #pragma unroll
  for (int r = 0; r < 4; ++r) {
    const int p    = tid + (r << 8);   // 0..1023
    const int b    = p >> 6;
    const int coll = p & 63;
    const int o    = half * 64 + coll;
    const float gi = gb[0 * 1040 + b * 65 + coll];
    const float go = gb[1 * 1040 + b * 65 + coll];
    const float gf = gb[2 * 1040 + b * 65 + coll];
    const float gc = gb[3 * 1040 + b * 65 + coll];
    const float it = fsigmoid(gi);
    const float ot = fsigmoid(go);
    const float ft = fsigmoid(gf);
    const float ch = ftanh(gc);
    const float cp = ct_1[nbase + o];
    const float ct = ft * cp + it * ch;
    const float ht = ot * ftanh(ct);
    const size_t oidx = (size_t)b * ((size_t)NS * OUT) + nbase + o;
    out[oidx] = ht;                              // ht
    out[(size_t)B * NS * OUT + oidx] = ct;       // ct
  }
}
}  // namespace

extern "C" void kernel_launch(void* const* d_in, const int* in_sizes, int n_in,
                              void* d_out, int out_size, void* d_ws, size_t ws_size,
                              hipStream_t stream) {
  const float* xt     = (const float*)d_in[0];
  const float* hidden = (const float*)d_in[1];
  const float* ct_1   = (const float*)d_in[2];
  const float* Wi     = (const float*)d_in[3];
  const float* bi     = (const float*)d_in[4];
  const float* Wo     = (const float*)d_in[5];
  const float* bo     = (const float*)d_in[6];
  const float* Wf     = (const float*)d_in[7];
  const float* bf     = (const float*)d_in[8];
  const float* Wc     = (const float*)d_in[9];
  const float* bc     = (const float*)d_in[10];

  lstm_kernel<<<2 * NS, 256, 0, stream>>>(xt, hidden, ct_1, Wi, bi, Wo, bo,
                                          Wf, bf, Wc, bc,
                                          (float*)d_out);
}

// Round 15
// 97.155 us; speedup vs baseline: 1.1278x; 1.1278x over previous
//
#include <hip/hip_runtime.h>
#include <hip/hip_bf16.h>

namespace {
constexpr int B   = 16;
constexpr int NS  = 1000;
constexpr int IN  = 128;
constexpr int OUT = 128;
constexpr int K   = 256;   // IN + OUT

typedef __attribute__((ext_vector_type(8))) short short8;
typedef __attribute__((ext_vector_type(4))) float f32x4;

__device__ __forceinline__ float fsigmoid(float x) {
  return 1.0f / (1.0f + __expf(-x));
}
__device__ __forceinline__ float ftanh(float x) {
  return 2.0f / (1.0f + __expf(-2.0f * x)) - 1.0f;
}
// fp32 -> bf16 round-to-nearest-even (bit pattern)
__device__ __forceinline__ unsigned int f2bf(float f) {
  unsigned int u = __builtin_bit_cast(unsigned int, f);
  u += 0x7fffu + ((u >> 16) & 1u);
  return u >> 16;
}
__device__ __forceinline__ unsigned int pack2(float lo, float hi) {
  return f2bf(lo) | (f2bf(hi) << 16);
}

// Block = stock n. 8 waves = gate (wid>>1) x col-half (wid&1).
// Identical to round-12 kernel (best: 107.98 us) EXCEPT: weight stage
// loads carry aux=2 (NT cache policy) — weights are a 524 MB/call
// single-use stream; NT stops them thrashing L3 between graph replays.
// A/B verification: FETCH_SIZE should ~double to ~540 MB if NT takes.
__global__ __launch_bounds__(512, 4) void lstm_kernel(
    const float* __restrict__ xt, const float* __restrict__ hidden,
    const float* __restrict__ ct_1,
    const float* __restrict__ Wi, const float* __restrict__ bi,
    const float* __restrict__ Wo, const float* __restrict__ bo,
    const float* __restrict__ Wf, const float* __restrict__ bfp,
    const float* __restrict__ Wc, const float* __restrict__ bc,
    float* __restrict__ out) {
  __shared__ __align__(16) unsigned char smem[65536];

  const int n   = blockIdx.x;
  const int tid = threadIdx.x;
  const int wid  = tid >> 6;   // 0..7
  const int g    = wid >> 1;   // gate
  const int half = wid & 1;    // column half (cols half*64 .. +63)
  const int l    = tid & 63;
  const int g2   = l >> 4;     // k-octet in frags / row-sub in staging
  const int c16  = l & 15;     // frag column / colquad in staging

  const float* Wg = (g == 0) ? Wi : (g == 1) ? Wo : (g == 2) ? Wf : Wc;
  const float* bg = (g == 0) ? bi : (g == 1) ? bo : (g == 2) ? bfp : bc;

  unsigned char* wbuf = smem + (wid << 13);          // this wave's 8KB buffer
  const float* wcb = Wg + (size_t)n * (K * OUT) + half * 64;

  // ---- stage chunk r (rows r*32..r*32+31, 64 cols, fp32) : 8 global_load_lds
  auto stage_chunk = [&](int r) {
    #pragma unroll
    for (int i = 0; i < 8; ++i) {
      const int cq = (c16 + ((i >> 1) << 2)) & 15;   // source col rotation
      const float* src =
          wcb + (size_t)((r << 5) + (i << 2) + g2) * OUT + (cq << 2);
      __builtin_amdgcn_global_load_lds(
          (const __attribute__((address_space(1))) void*)src,
          (__attribute__((address_space(3))) void*)(wbuf + (i << 10)),
          16, 0, 2 /* NT: single-use stream, don't retain in L2/L3 */);
    }
  };
  // ---- A-frag for chunk r: xh[row=c16][k=r*32+g2*8 .. +7] from global ----
  auto load_a = [&](int r, float4& x0, float4& x1) {
    const int k = (r << 5) + (g2 << 3);
    const float* s = (k < IN) ? (xt + ((size_t)c16 * NS + n) * IN + k)
                              : (hidden + (size_t)n * OUT + (k - IN));
    x0 = *reinterpret_cast<const float4*>(s);
    x1 = *reinterpret_cast<const float4*>(s + 4);
  };

  f32x4 acc[4] = {f32x4{0,0,0,0}, f32x4{0,0,0,0}, f32x4{0,0,0,0}, f32x4{0,0,0,0}};

  stage_chunk(0);
  float4 a0, a1;
  load_a(0, a0, a1);

  #pragma unroll 1
  for (int r = 0; r < 8; ++r) {
    asm volatile("s_waitcnt vmcnt(0)" ::: "memory");   // chunk r + A r resident

    // B-frags: 8 ds_read_b32 per tile; bank = rotated 2-way (free)
    float wv[4][8];
    #pragma unroll
    for (int t = 0; t < 4; ++t) {
      const int pb = (((((t << 2) + (c16 >> 2)) - (g2 << 2)) & 15) << 4) +
                     ((c16 & 3) << 2);
      #pragma unroll
      for (int j = 0; j < 8; ++j)
        wv[t][j] = *reinterpret_cast<const float*>(
            wbuf + (g2 << 11) + (j << 8) + pb);
    }
    uint4 au;
    au.x = pack2(a0.x, a0.y); au.y = pack2(a0.z, a0.w);
    au.z = pack2(a1.x, a1.y); au.w = pack2(a1.z, a1.w);
    const short8 af = __builtin_bit_cast(short8, au);

    asm volatile("s_waitcnt lgkmcnt(0)" ::: "memory"); // ds_reads drained
    float4 na0 = a0, na1 = a1;
    if (r < 7) {
      stage_chunk(r + 1);        // overwrite safe: reads complete
      load_a(r + 1, na0, na1);
    }

    #pragma unroll
    for (int t = 0; t < 4; ++t) {
      uint4 bu;
      bu.x = pack2(wv[t][0], wv[t][1]);
      bu.y = pack2(wv[t][2], wv[t][3]);
      bu.z = pack2(wv[t][4], wv[t][5]);
      bu.w = pack2(wv[t][6], wv[t][7]);
      acc[t] = __builtin_amdgcn_mfma_f32_16x16x32_bf16(
          af, __builtin_bit_cast(short8, bu), acc[t], 0, 0, 0);
    }
    a0 = na0; a1 = na1;          // waits (if any) land after the MFMAs
  }

  // ---- epilogue: overlay gbuf (idx = g*2064 + b*129 + col) ----
  __syncthreads();   // all waves' LDS reads complete before overwrite
  float* gb = reinterpret_cast<float*>(smem);
  #pragma unroll
  for (int t = 0; t < 4; ++t) {
    const int colg = (half << 6) + (t << 4) + c16;     // global col 0..127
    const float bias = bg[(size_t)n * OUT + colg];
    #pragma unroll
    for (int r2 = 0; r2 < 4; ++r2) {
      const int b = (g2 << 2) + r2;                    // C/D: row=(lane>>4)*4+reg
      gb[g * 2064 + b * 129 + colg] = acc[t][r2] + bias;
    }
  }
  __syncthreads();

  // ---- combine gates, write ht and ct (fp32 outputs) ----
  const size_t nbase = (size_t)n * OUT;
  #pragma unroll
  for (int r = 0; r < 4; ++r) {
    const int p = tid + (r << 9);   // 0..2047
    const int b = p >> 7;
    const int o = p & 127;
    const float gi = gb[0 * 2064 + b * 129 + o];
    const float go = gb[1 * 2064 + b * 129 + o];
    const float gf = gb[2 * 2064 + b * 129 + o];
    const float gc = gb[3 * 2064 + b * 129 + o];
    const float it = fsigmoid(gi);
    const float ot = fsigmoid(go);
    const float ft = fsigmoid(gf);
    const float ch = ftanh(gc);
    const float cp = ct_1[nbase + o];
    const float ct = ft * cp + it * ch;
    const float ht = ot * ftanh(ct);
    const size_t oidx = (size_t)b * ((size_t)NS * OUT) + nbase + o;
    out[oidx] = ht;                              // ht
    out[(size_t)B * NS * OUT + oidx] = ct;       // ct
  }
}
}  // namespace

extern "C" void kernel_launch(void* const* d_in, const int* in_sizes, int n_in,
                              void* d_out, int out_size, void* d_ws, size_t ws_size,
                              hipStream_t stream) {
  const float* xt     = (const float*)d_in[0];
  const float* hidden = (const float*)d_in[1];
  const float* ct_1   = (const float*)d_in[2];
  const float* Wi     = (const float*)d_in[3];
  const float* bi     = (const float*)d_in[4];
  const float* Wo     = (const float*)d_in[5];
  const float* bo     = (const float*)d_in[6];
  const float* Wf     = (const float*)d_in[7];
  const float* bf     = (const float*)d_in[8];
  const float* Wc     = (const float*)d_in[9];
  const float* bc     = (const float*)d_in[10];

  lstm_kernel<<<NS, 512, 0, stream>>>(xt, hidden, ct_1, Wi, bi, Wo, bo,
                                      Wf, bf, Wc, bc,
                                      (float*)d_out);
}